// Round 13
// baseline (890.224 us; speedup 1.0000x reference)
//
#include <hip/hip_runtime.h>
#include <hip/hip_bf16.h>

#define N_NODES 100000
#define N_EDGES 1600000
#define N_GRAPHS 1024
#define F_NODE 16
#define F_EDGE 8
#define F_GRAPH 10
#define HD 64
#define HD2 128
#define GEN_EPS 1e-7f
#define SCAN_NBLK ((N_NODES + 255) / 256)   // 391

typedef unsigned short u16;
typedef unsigned int u32;

__device__ __forceinline__ u16 f2bf(float x) {   // RNE bf16 (finite inputs)
    u32 u = __float_as_uint(x);
    return (u16)((u + 0x7FFFu + ((u >> 16) & 1u)) >> 16);
}
__device__ __forceinline__ float bf2f(u16 u) {
    return __uint_as_float(((u32)u) << 16);
}

// h[n][f] = node_b[f] + sum_k x[n][k]*node_W[k][f]; also emits bf16 mirror hb.
__global__ void __launch_bounds__(256) k_node_embed(
        const float* __restrict__ x, const float* __restrict__ W,
        const float* __restrict__ b, float* __restrict__ h,
        u16* __restrict__ hb) {
    __shared__ float sW[F_NODE * HD];
    __shared__ float sb[HD];
    for (int i = threadIdx.x; i < F_NODE * HD; i += 256) sW[i] = W[i];
    if (threadIdx.x < HD) sb[threadIdx.x] = b[threadIdx.x];
    __syncthreads();
    int t = blockIdx.x * 256 + threadIdx.x;
    if (t >= N_NODES * HD) return;
    int n = t >> 6, f = t & 63;
    const float* xr = x + (size_t)n * F_NODE;
    float acc = sb[f];
#pragma unroll
    for (int k = 0; k < F_NODE; k++) acc += xr[k] * sW[k * HD + f];
    h[t] = acc;
    hb[t] = f2bf(acc);
}

// ---- CSR build ----
__global__ void __launch_bounds__(256) k_hist(
        const int* __restrict__ dst, int* __restrict__ deg,
        int* __restrict__ rank) {
    int e = blockIdx.x * 256 + threadIdx.x;
    if (e >= N_EDGES) return;
    rank[e] = atomicAdd(&deg[dst[e]], 1);
}

__global__ void __launch_bounds__(256) k_scan1(
        const int* __restrict__ deg, int* __restrict__ bsum) {
    __shared__ int red[256];
    int t = threadIdx.x;
    int g = blockIdx.x * 256 + t;
    red[t] = (g < N_NODES) ? deg[g] : 0;
    __syncthreads();
    for (int s = 128; s > 0; s >>= 1) {
        if (t < s) red[t] += red[t + s];
        __syncthreads();
    }
    if (t == 0) bsum[blockIdx.x] = red[0];
}

__global__ void __launch_bounds__(512) k_scan2(
        const int* __restrict__ bsum, int* __restrict__ bpre) {
    __shared__ int sh[512];
    int t = threadIdx.x;
    int v = (t < SCAN_NBLK) ? bsum[t] : 0;
    sh[t] = v;
    __syncthreads();
    for (int d = 1; d < 512; d <<= 1) {
        int u = (t >= d) ? sh[t - d] : 0;
        __syncthreads();
        sh[t] += u;
        __syncthreads();
    }
    if (t < SCAN_NBLK) bpre[t] = sh[t] - v;   // exclusive
}

__global__ void __launch_bounds__(256) k_scan3(
        const int* __restrict__ deg, const int* __restrict__ bpre,
        int* __restrict__ off) {
    __shared__ int sh[256];
    int t = threadIdx.x;
    int g = blockIdx.x * 256 + t;
    int v = (g < N_NODES) ? deg[g] : 0;
    sh[t] = v;
    __syncthreads();
    for (int d = 1; d < 256; d <<= 1) {
        int u = (t >= d) ? sh[t - d] : 0;
        __syncthreads();
        sh[t] += u;
        __syncthreads();
    }
    int incl = sh[t];
    int base = bpre[blockIdx.x];
    if (g < N_NODES) off[g] = base + incl - v;
    if (g == N_NODES - 1) off[N_NODES] = base + incl;
}

// Scatter with ONE random 32B store per edge; 17-bit src hidden in the
// mantissa LSBs of ea[0..5] (rel. perturbation <= 4e-7).
__global__ void __launch_bounds__(256) k_scatter(
        const int* __restrict__ src, const int* __restrict__ dst,
        const int* __restrict__ rank, const int* __restrict__ off,
        const float* __restrict__ eattr,
        unsigned int* __restrict__ rec) {
    int e = blockIdx.x * 256 + threadIdx.x;
    if (e >= N_EDGES) return;
    const uint4* ap = reinterpret_cast<const uint4*>(eattr + (size_t)e * F_EDGE);
    uint4 a0 = ap[0], a1 = ap[1];           // coalesced 32B read
    unsigned int s = (unsigned int)src[e];  // < 2^17
    a0.x = (a0.x & ~7u) | (s & 7u);
    a0.y = (a0.y & ~7u) | ((s >> 3) & 7u);
    a0.z = (a0.z & ~7u) | ((s >> 6) & 7u);
    a0.w = (a0.w & ~7u) | ((s >> 9) & 7u);
    a1.x = (a1.x & ~7u) | ((s >> 12) & 7u);
    a1.y = (a1.y & ~7u) | ((s >> 15) & 3u);  // bits 15..16
    int pos = off[dst[e]] + rank[e];
    uint4* op = reinterpret_cast<uint4*>(rec + (size_t)pos * 8);
    op[0] = a0;                              // one 32B sector
    op[1] = a1;
}

__device__ __forceinline__ float u2f(unsigned int u) {
    return __uint_as_float(u);
}

// ---- GENConv aggregation: one wave per destination node, lane = feature.
// ALL edges processed in clamped+masked batches of 8: the final partial
// batch gets the same 8-deep memory-level parallelism as full batches
// (the old serial remainder loop paid the full s_load->decode->gather
// latency chain per edge). Mask = 1 v_cndmask per edge.
__global__ void __launch_bounds__(256) k_gen_agg(
        const float* __restrict__ h, const u16* __restrict__ hb,
        const int* __restrict__ off,
        const unsigned int* __restrict__ rec,
        const float* __restrict__ eW, const float* __restrict__ eb,
        float* __restrict__ outb) {
    int n = blockIdx.x * 4 + (threadIdx.x >> 6);
    if (n >= N_NODES) return;
    int f = threadIdx.x & 63;
    float w[F_EDGE];
#pragma unroll
    for (int k = 0; k < F_EDGE; k++) w[k] = eW[k * HD + f];
    float bf = eb[f];
    int nu = __builtin_amdgcn_readfirstlane(n);
    int beg = off[nu], end = off[nu + 1];
    float den = 0.f, nm = 0.f;
    for (int i = beg; i < end; i += 8) {
        int rem = end - i;                   // >= 1 (wave-uniform)
        uint4 q0[8], q1[8];
#pragma unroll
        for (int u = 0; u < 8; u++) {
            int idx = (i + u < end) ? (i + u) : (end - 1);   // clamp (SALU)
            const uint4* rp = reinterpret_cast<const uint4*>(
                rec + (size_t)idx * 8);
            q0[u] = rp[0];
            q1[u] = rp[1];
        }
        int s[8];
#pragma unroll
        for (int u = 0; u < 8; u++) {
            s[u] = (int)((q0[u].x & 7u) | ((q0[u].y & 7u) << 3)
                       | ((q0[u].z & 7u) << 6) | ((q0[u].w & 7u) << 9)
                       | ((q1[u].x & 7u) << 12) | ((q1[u].y & 3u) << 15));
        }
        float hv[8];
#pragma unroll
        for (int u = 0; u < 8; u++) hv[u] = bf2f(hb[(size_t)s[u] * HD + f]);
#pragma unroll
        for (int u = 0; u < 8; u++) {
            float ea = bf + u2f(q0[u].x) * w[0] + u2f(q0[u].y) * w[1]
                          + u2f(q0[u].z) * w[2] + u2f(q0[u].w) * w[3]
                          + u2f(q1[u].x) * w[4] + u2f(q1[u].y) * w[5]
                          + u2f(q1[u].z) * w[6] + u2f(q1[u].w) * w[7];
            float m = fmaxf(hv[u] + ea, 0.f) + GEN_EPS;
            float ev = __expf(m);
            ev = (u < rem) ? ev : 0.f;       // phantom-slot mask
            den += ev;
            nm += m * ev;
        }
    }
    size_t idx = (size_t)n * HD + f;
    outb[idx] = h[idx] + nm / fmaxf(den, 1e-16f);
}

// ---- MLP stage 1: hid[n][j] = relu(in[n][:] @ W1[:, j] + b1[j]), K=64, J=128.
__global__ void __launch_bounds__(256) k_mlp1(
        const float* __restrict__ inb,
        const float* __restrict__ W1, const float* __restrict__ b1,
        float* __restrict__ hid) {
    __shared__ float sIn[HD][68];      // [f][n], 17.4 KB
    __shared__ float sW1[HD * HD2];    // 32 KB
    __shared__ float sb1[HD2];
    int tid = threadIdx.x;
    int n0 = blockIdx.x * 64;
    for (int i = tid; i < HD * HD2; i += 256) sW1[i] = W1[i];
    if (tid < HD2) sb1[tid] = b1[tid];
    {
        int n = tid & 63;
        int q = tid >> 6;              // 0..3
        int gn = n0 + n;
#pragma unroll
        for (int g = 0; g < 4; g++) {
            int fqi = g * 4 + q;       // 0..15
            float4 v = (gn < N_NODES)
                ? reinterpret_cast<const float4*>(inb + (size_t)gn * HD)[fqi]
                : make_float4(0.f, 0.f, 0.f, 0.f);
            sIn[fqi * 4 + 0][n] = v.x; sIn[fqi * 4 + 1][n] = v.y;
            sIn[fqi * 4 + 2][n] = v.z; sIn[fqi * 4 + 3][n] = v.w;
        }
    }
    __syncthreads();
    int ng = tid >> 5, jg = tid & 31;
    int nb = ng * 8, jb = jg * 4;
    float acc[8][4];
#pragma unroll
    for (int i = 0; i < 8; i++)
#pragma unroll
        for (int q = 0; q < 4; q++) acc[i][q] = sb1[jb + q];
#pragma unroll 2
    for (int f = 0; f < HD; f++) {
        float4 w  = *reinterpret_cast<const float4*>(&sW1[f * HD2 + jb]);
        float4 x0 = *reinterpret_cast<const float4*>(&sIn[f][nb]);
        float4 x1 = *reinterpret_cast<const float4*>(&sIn[f][nb + 4]);
        float xv[8] = {x0.x, x0.y, x0.z, x0.w, x1.x, x1.y, x1.z, x1.w};
#pragma unroll
        for (int i = 0; i < 8; i++) {
            acc[i][0] += xv[i] * w.x;
            acc[i][1] += xv[i] * w.y;
            acc[i][2] += xv[i] * w.z;
            acc[i][3] += xv[i] * w.w;
        }
    }
#pragma unroll
    for (int i = 0; i < 8; i++) {
        int gn = n0 + nb + i;
        if (gn < N_NODES) {
            float4 o;
            o.x = fmaxf(acc[i][0], 0.f);
            o.y = fmaxf(acc[i][1], 0.f);
            o.z = fmaxf(acc[i][2], 0.f);
            o.w = fmaxf(acc[i][3], 0.f);
            *reinterpret_cast<float4*>(hid + (size_t)gn * HD2 + jb) = o;
        }
    }
}

// ---- MLP stage 2: h'[n][j] = relu(hid[n][:] @ W2[:, j] + b2[j]), K=128, J=64.
// Also emits the bf16 mirror hb for the next layer's gather.
__global__ void __launch_bounds__(256) k_mlp2(
        const float* __restrict__ hid,
        const float* __restrict__ W2, const float* __restrict__ b2,
        float* __restrict__ hout, u16* __restrict__ hbout) {
    __shared__ float sH[HD2][68];      // [f2][n], 34.8 KB
    __shared__ float sW2[HD2 * HD];    // 32 KB
    __shared__ float sb2[HD];
    int tid = threadIdx.x;
    int n0 = blockIdx.x * 64;
    for (int i = tid; i < HD2 * HD; i += 256) sW2[i] = W2[i];
    if (tid < HD) sb2[tid] = b2[tid];
    {
        int n = tid & 63;
        int q = tid >> 6;              // 0..3
        int gn = n0 + n;
#pragma unroll
        for (int g = 0; g < 8; g++) {
            int fqi = g * 4 + q;       // 0..31
            float4 v = (gn < N_NODES)
                ? reinterpret_cast<const float4*>(hid + (size_t)gn * HD2)[fqi]
                : make_float4(0.f, 0.f, 0.f, 0.f);
            sH[fqi * 4 + 0][n] = v.x; sH[fqi * 4 + 1][n] = v.y;
            sH[fqi * 4 + 2][n] = v.z; sH[fqi * 4 + 3][n] = v.w;
        }
    }
    __syncthreads();
    int ng = tid >> 4, jg = tid & 15;
    int nb = ng * 4, jb = jg * 4;
    float acc[4][4];
#pragma unroll
    for (int i = 0; i < 4; i++)
#pragma unroll
        for (int q = 0; q < 4; q++) acc[i][q] = sb2[jb + q];
#pragma unroll 2
    for (int f2 = 0; f2 < HD2; f2++) {
        float4 w = *reinterpret_cast<const float4*>(&sW2[f2 * HD + jb]);
        float4 x = *reinterpret_cast<const float4*>(&sH[f2][nb]);
        float xv[4] = {x.x, x.y, x.z, x.w};
#pragma unroll
        for (int i = 0; i < 4; i++) {
            acc[i][0] += xv[i] * w.x;
            acc[i][1] += xv[i] * w.y;
            acc[i][2] += xv[i] * w.z;
            acc[i][3] += xv[i] * w.w;
        }
    }
#pragma unroll
    for (int i = 0; i < 4; i++) {
        int gn = n0 + nb + i;
        if (gn < N_NODES) {
            float4 o;
            o.x = fmaxf(acc[i][0], 0.f);
            o.y = fmaxf(acc[i][1], 0.f);
            o.z = fmaxf(acc[i][2], 0.f);
            o.w = fmaxf(acc[i][3], 0.f);
            *reinterpret_cast<float4*>(hout + (size_t)gn * HD + jb) = o;
            ushort4 ob;
            ob.x = f2bf(o.x); ob.y = f2bf(o.y);
            ob.z = f2bf(o.z); ob.w = f2bf(o.w);
            *reinterpret_cast<ushort4*>(hbout + (size_t)gn * HD + jb) = ob;
        }
    }
}

// One wave per graph; range via inline binary search on sorted batch.
__global__ void __launch_bounds__(256) k_pool(
        const float* __restrict__ h, const int* __restrict__ batch,
        float* __restrict__ pooled) {
    int g = blockIdx.x * 4 + (threadIdx.x >> 6);
    if (g >= N_GRAPHS) return;
    int f = threadIdx.x & 63;
    int lo = 0, hi = N_NODES;
    while (lo < hi) {
        int mid = (lo + hi) >> 1;
        if (batch[mid] < g) lo = mid + 1; else hi = mid;
    }
    int b = lo;
    int lo2 = b, hi2 = N_NODES;
    while (lo2 < hi2) {
        int mid = (lo2 + hi2) >> 1;
        if (batch[mid] < g + 1) lo2 = mid + 1; else hi2 = mid;
    }
    int e = lo2;
    float s = 0.f;
    for (int n = b; n < e; n++) s += h[(size_t)n * HD + f];
    float cnt = fmaxf((float)(e - b), 1.f);
    pooled[(size_t)g * HD + f] = s / cnt;
}

__global__ void __launch_bounds__(64) k_head(
        const float* __restrict__ pooled, const float* __restrict__ gattr,
        const float* __restrict__ d1W, const float* __restrict__ d1b,
        const float* __restrict__ d2W, const float* __restrict__ d2b,
        const float* __restrict__ oW, const float* __restrict__ ob,
        float* __restrict__ out) {
    int g = blockIdx.x;
    __shared__ float si[HD + F_GRAPH];
    __shared__ float s1[32], s2[32];
    int t = threadIdx.x;
    if (t < HD) si[t] = pooled[(size_t)g * HD + t];
    if (t < F_GRAPH) si[HD + t] = gattr[(size_t)g * F_GRAPH + t];
    __syncthreads();
    if (t < 32) {
        float acc = d1b[t];
        for (int i = 0; i < HD + F_GRAPH; i++) acc += si[i] * d1W[i * 32 + t];
        s1[t] = fmaxf(acc, 0.f);
    }
    __syncthreads();
    if (t < 32) {
        float acc = d2b[t];
        for (int i = 0; i < 32; i++) acc += s1[i] * d2W[i * 32 + t];
        s2[t] = fmaxf(acc, 0.f);
    }
    __syncthreads();
    if (t == 0) {
        float acc = ob[0];
        for (int i = 0; i < 32; i++) acc += s2[i] * oW[i];
        out[g] = 1.f / (1.f + __expf(-acc));
    }
}

extern "C" void kernel_launch(void* const* d_in, const int* in_sizes, int n_in,
                              void* d_out, int out_size, void* d_ws, size_t ws_size,
                              hipStream_t stream) {
    const float* x     = (const float*)d_in[0];
    const float* eattr = (const float*)d_in[1];
    const float* gattr = (const float*)d_in[2];
    const int*   eidx  = (const int*)d_in[3];
    const int*   batch = (const int*)d_in[4];
    const float* nodeW = (const float*)d_in[5];
    const float* nodeb = (const float*)d_in[6];
    const float* edgeW = (const float*)d_in[7];
    const float* edgeb = (const float*)d_in[8];
    const float* cW1[3] = {(const float*)d_in[9],  (const float*)d_in[13], (const float*)d_in[17]};
    const float* cb1[3] = {(const float*)d_in[10], (const float*)d_in[14], (const float*)d_in[18]};
    const float* cW2[3] = {(const float*)d_in[11], (const float*)d_in[15], (const float*)d_in[19]};
    const float* cb2[3] = {(const float*)d_in[12], (const float*)d_in[16], (const float*)d_in[20]};
    const float* d1W = (const float*)d_in[21];
    const float* d1b = (const float*)d_in[22];
    const float* d2W = (const float*)d_in[23];
    const float* d2b = (const float*)d_in[24];
    const float* oW  = (const float*)d_in[25];
    const float* ob  = (const float*)d_in[26];

    const int* src = eidx;
    const int* dst = eidx + N_EDGES;

    // workspace layout
    char* p = (char*)d_ws;
    float* h      = (float*)p; p += (size_t)N_NODES * HD * 4;       // 25.6 MB
    float* outb   = (float*)p; p += (size_t)N_NODES * HD * 4;       // 25.6 MB
    float* hid    = (float*)p; p += (size_t)N_NODES * HD2 * 4;      // 51.2 MB
    unsigned int* rec = (unsigned int*)p; p += (size_t)N_EDGES * F_EDGE * 4; // 51.2 MB
    u16*   hb     = (u16*)p;   p += (size_t)N_NODES * HD * 2;       // 12.8 MB
    float* pooled = (float*)p; p += (size_t)N_GRAPHS * HD * 4;
    int*   off    = (int*)p;   p += (size_t)(N_NODES + 1) * 4;
    int*   deg    = (int*)p;   p += (size_t)N_NODES * 4;
    int*   rank   = (int*)p;   p += (size_t)N_EDGES * 4;            // 6.4 MB
    int*   bsum   = (int*)p;   p += (size_t)(SCAN_NBLK + 1) * 4;
    int*   bpre   = (int*)p;   p += (size_t)(SCAN_NBLK + 1) * 4;

    const int EB = (N_EDGES + 255) / 256;
    const int NB64 = (N_NODES + 63) / 64;

    k_node_embed<<<(N_NODES * HD + 255) / 256, 256, 0, stream>>>(x, nodeW, nodeb, h, hb);

    // CSR build (atomic-free scatter via hist-captured ranks)
    hipMemsetAsync(deg, 0, (size_t)N_NODES * 4, stream);
    k_hist<<<EB, 256, 0, stream>>>(dst, deg, rank);
    k_scan1<<<SCAN_NBLK, 256, 0, stream>>>(deg, bsum);
    k_scan2<<<1, 512, 0, stream>>>(bsum, bpre);
    k_scan3<<<SCAN_NBLK, 256, 0, stream>>>(deg, bpre, off);
    k_scatter<<<EB, 256, 0, stream>>>(src, dst, rank, off, eattr, rec);

    for (int l = 0; l < 3; l++) {
        k_gen_agg<<<(N_NODES + 3) / 4, 256, 0, stream>>>(
            h, hb, off, rec, edgeW, edgeb, outb);
        k_mlp1<<<NB64, 256, 0, stream>>>(outb, cW1[l], cb1[l], hid);
        k_mlp2<<<NB64, 256, 0, stream>>>(hid, cW2[l], cb2[l], h, hb);
    }

    k_pool<<<(N_GRAPHS + 3) / 4, 256, 0, stream>>>(h, batch, pooled);
    k_head<<<N_GRAPHS, 64, 0, stream>>>(pooled, gattr,
                                        d1W, d1b, d2W, d2b, oW, ob,
                                        (float*)d_out);
}

// Round 14
// 727.674 us; speedup vs baseline: 1.2234x; 1.2234x over previous
//
#include <hip/hip_runtime.h>
#include <hip/hip_bf16.h>

#define N_NODES 100000
#define N_EDGES 1600000
#define N_GRAPHS 1024
#define F_NODE 16
#define F_EDGE 8
#define F_GRAPH 10
#define HD 64
#define HD2 128
#define GEN_EPS 1e-7f
#define SCAN_NBLK ((N_NODES + 255) / 256)   // 391

typedef unsigned short u16;
typedef unsigned int u32;
typedef __attribute__((ext_vector_type(8))) short short8;
typedef __attribute__((ext_vector_type(4))) float floatx4;

__device__ __forceinline__ u16 f2bf(float x) {   // RNE bf16 (finite inputs)
    u32 u = __float_as_uint(x);
    return (u16)((u + 0x7FFFu + ((u >> 16) & 1u)) >> 16);
}
__device__ __forceinline__ float bf2f(u16 u) {
    return __uint_as_float(((u32)u) << 16);
}

// h[n][f] = node_b[f] + sum_k x[n][k]*node_W[k][f]; also emits bf16 mirror hb.
__global__ void __launch_bounds__(256) k_node_embed(
        const float* __restrict__ x, const float* __restrict__ W,
        const float* __restrict__ b, float* __restrict__ h,
        u16* __restrict__ hb) {
    __shared__ float sW[F_NODE * HD];
    __shared__ float sb[HD];
    for (int i = threadIdx.x; i < F_NODE * HD; i += 256) sW[i] = W[i];
    if (threadIdx.x < HD) sb[threadIdx.x] = b[threadIdx.x];
    __syncthreads();
    int t = blockIdx.x * 256 + threadIdx.x;
    if (t >= N_NODES * HD) return;
    int n = t >> 6, f = t & 63;
    const float* xr = x + (size_t)n * F_NODE;
    float acc = sb[f];
#pragma unroll
    for (int k = 0; k < F_NODE; k++) acc += xr[k] * sW[k * HD + f];
    h[t] = acc;
    hb[t] = f2bf(acc);
}

// ---- CSR build ----
__global__ void __launch_bounds__(256) k_hist(
        const int* __restrict__ dst, int* __restrict__ deg,
        int* __restrict__ rank) {
    int e = blockIdx.x * 256 + threadIdx.x;
    if (e >= N_EDGES) return;
    rank[e] = atomicAdd(&deg[dst[e]], 1);
}

__global__ void __launch_bounds__(256) k_scan1(
        const int* __restrict__ deg, int* __restrict__ bsum) {
    __shared__ int red[256];
    int t = threadIdx.x;
    int g = blockIdx.x * 256 + t;
    red[t] = (g < N_NODES) ? deg[g] : 0;
    __syncthreads();
    for (int s = 128; s > 0; s >>= 1) {
        if (t < s) red[t] += red[t + s];
        __syncthreads();
    }
    if (t == 0) bsum[blockIdx.x] = red[0];
}

__global__ void __launch_bounds__(512) k_scan2(
        const int* __restrict__ bsum, int* __restrict__ bpre) {
    __shared__ int sh[512];
    int t = threadIdx.x;
    int v = (t < SCAN_NBLK) ? bsum[t] : 0;
    sh[t] = v;
    __syncthreads();
    for (int d = 1; d < 512; d <<= 1) {
        int u = (t >= d) ? sh[t - d] : 0;
        __syncthreads();
        sh[t] += u;
        __syncthreads();
    }
    if (t < SCAN_NBLK) bpre[t] = sh[t] - v;   // exclusive
}

__global__ void __launch_bounds__(256) k_scan3(
        const int* __restrict__ deg, const int* __restrict__ bpre,
        int* __restrict__ off) {
    __shared__ int sh[256];
    int t = threadIdx.x;
    int g = blockIdx.x * 256 + t;
    int v = (g < N_NODES) ? deg[g] : 0;
    sh[t] = v;
    __syncthreads();
    for (int d = 1; d < 256; d <<= 1) {
        int u = (t >= d) ? sh[t - d] : 0;
        __syncthreads();
        sh[t] += u;
        __syncthreads();
    }
    int incl = sh[t];
    int base = bpre[blockIdx.x];
    if (g < N_NODES) off[g] = base + incl - v;
    if (g == N_NODES - 1) off[N_NODES] = base + incl;
}

// Scatter with ONE random 32B store per edge; 17-bit src hidden in the
// mantissa LSBs of ea[0..5] (rel. perturbation <= 4e-7).
__global__ void __launch_bounds__(256) k_scatter(
        const int* __restrict__ src, const int* __restrict__ dst,
        const int* __restrict__ rank, const int* __restrict__ off,
        const float* __restrict__ eattr,
        unsigned int* __restrict__ rec) {
    int e = blockIdx.x * 256 + threadIdx.x;
    if (e >= N_EDGES) return;
    const uint4* ap = reinterpret_cast<const uint4*>(eattr + (size_t)e * F_EDGE);
    uint4 a0 = ap[0], a1 = ap[1];           // coalesced 32B read
    unsigned int s = (unsigned int)src[e];  // < 2^17
    a0.x = (a0.x & ~7u) | (s & 7u);
    a0.y = (a0.y & ~7u) | ((s >> 3) & 7u);
    a0.z = (a0.z & ~7u) | ((s >> 6) & 7u);
    a0.w = (a0.w & ~7u) | ((s >> 9) & 7u);
    a1.x = (a1.x & ~7u) | ((s >> 12) & 7u);
    a1.y = (a1.y & ~7u) | ((s >> 15) & 3u);  // bits 15..16
    int pos = off[dst[e]] + rank[e];
    uint4* op = reinterpret_cast<uint4*>(rec + (size_t)pos * 8);
    op[0] = a0;                              // one 32B sector
    op[1] = a1;
}

__device__ __forceinline__ float u2f(unsigned int u) {
    return __uint_as_float(u);
}

// ---- GENConv aggregation (R12 version — measured 104.8us; masked batching
// regressed it in R13 by adding phantom work). One wave per destination node,
// lane = feature; rec loads scalarize (s_load, SGPR decode); message h from
// bf16 mirror; root add reads fp32 h sequentially (exact).
__global__ void __launch_bounds__(256) k_gen_agg(
        const float* __restrict__ h, const u16* __restrict__ hb,
        const int* __restrict__ off,
        const unsigned int* __restrict__ rec,
        const float* __restrict__ eW, const float* __restrict__ eb,
        float* __restrict__ outb) {
    int n = blockIdx.x * 4 + (threadIdx.x >> 6);
    if (n >= N_NODES) return;
    int f = threadIdx.x & 63;
    float w[F_EDGE];
#pragma unroll
    for (int k = 0; k < F_EDGE; k++) w[k] = eW[k * HD + f];
    float bf = eb[f];
    int nu = __builtin_amdgcn_readfirstlane(n);
    int beg = off[nu], end = off[nu + 1];
    float den = 0.f, nm = 0.f;
    int i = beg;
    for (; i + 8 <= end; i += 8) {
        uint4 q0[8], q1[8];
#pragma unroll
        for (int u = 0; u < 8; u++) {
            const uint4* rp = reinterpret_cast<const uint4*>(
                rec + (size_t)(i + u) * 8);
            q0[u] = rp[0];
            q1[u] = rp[1];
        }
        int s[8];
#pragma unroll
        for (int u = 0; u < 8; u++) {
            s[u] = (int)((q0[u].x & 7u) | ((q0[u].y & 7u) << 3)
                       | ((q0[u].z & 7u) << 6) | ((q0[u].w & 7u) << 9)
                       | ((q1[u].x & 7u) << 12) | ((q1[u].y & 3u) << 15));
        }
        float hv[8];
#pragma unroll
        for (int u = 0; u < 8; u++) hv[u] = bf2f(hb[(size_t)s[u] * HD + f]);
#pragma unroll
        for (int u = 0; u < 8; u++) {
            float ea = bf + u2f(q0[u].x) * w[0] + u2f(q0[u].y) * w[1]
                          + u2f(q0[u].z) * w[2] + u2f(q0[u].w) * w[3]
                          + u2f(q1[u].x) * w[4] + u2f(q1[u].y) * w[5]
                          + u2f(q1[u].z) * w[6] + u2f(q1[u].w) * w[7];
            float m = fmaxf(hv[u] + ea, 0.f) + GEN_EPS;
            float ev = __expf(m);
            den += ev;
            nm += m * ev;
        }
    }
    for (; i < end; i++) {
        const uint4* rp = reinterpret_cast<const uint4*>(rec + (size_t)i * 8);
        uint4 q0 = rp[0], q1 = rp[1];
        int s = (int)((q0.x & 7u) | ((q0.y & 7u) << 3)
                    | ((q0.z & 7u) << 6) | ((q0.w & 7u) << 9)
                    | ((q1.x & 7u) << 12) | ((q1.y & 3u) << 15));
        float hv = bf2f(hb[(size_t)s * HD + f]);
        float ea = bf + u2f(q0.x) * w[0] + u2f(q0.y) * w[1]
                      + u2f(q0.z) * w[2] + u2f(q0.w) * w[3]
                      + u2f(q1.x) * w[4] + u2f(q1.y) * w[5]
                      + u2f(q1.z) * w[6] + u2f(q1.w) * w[7];
        float m = fmaxf(hv + ea, 0.f) + GEN_EPS;
        float ev = __expf(m);
        den += ev;
        nm += m * ev;
    }
    size_t idx = (size_t)n * HD + f;
    outb[idx] = h[idx] + nm / fmaxf(den, 1e-16f);
}

// ---- MLP stage 1 (MFMA): hid[n][j] = relu(in[n][:]@W1[:,j]+b1[j]), K=64,J=128.
// bf16 16x16x32 MFMA. A-frag read direct from global (f32 -> bf16 in-reg);
// W1 transposed to LDS bf16 [j][k+8pad] so B-frags are one 16B read
// (2-way bank aliasing = free). hid stored bf16 (mlp2's A input).
// Layouts (verified, learn_hip m89/m120): A[m=lane&15][k=quad*8+j],
// B[n=lane&15][k=quad*8+j], D col=lane&15 row=quad*4+reg.
__global__ void __launch_bounds__(256) k_mlp1(
        const float* __restrict__ inb,
        const float* __restrict__ W1, const float* __restrict__ b1,
        u16* __restrict__ hid) {
    __shared__ u16 wB[HD2][HD + 8];   // [j][k], 128*72*2 = 18.4 KB
    __shared__ float sb1[HD2];
    int tid = threadIdx.x;
    for (int i = tid; i < HD * HD2; i += 256) {
        int f = i >> 7, j = i & 127;
        wB[j][f] = f2bf(W1[i]);
    }
    if (tid < HD2) sb1[tid] = b1[tid];
    __syncthreads();
    int wid = tid >> 6, lane = tid & 63;
    int quad = lane >> 4, lm = lane & 15;
    int n0 = blockIdx.x * 64 + wid * 16;
    if (n0 >= N_NODES) return;            // 100000 % 16 == 0: whole-tile guard
    int node = n0 + lm;
    short8 a[2];
    const float* ar = inb + (size_t)node * HD;
#pragma unroll
    for (int kk = 0; kk < 2; kk++) {
        const float4* p = reinterpret_cast<const float4*>(ar + kk * 32 + quad * 8);
        float4 v0 = p[0], v1 = p[1];
        short8 t;
        t[0] = (short)f2bf(v0.x); t[1] = (short)f2bf(v0.y);
        t[2] = (short)f2bf(v0.z); t[3] = (short)f2bf(v0.w);
        t[4] = (short)f2bf(v1.x); t[5] = (short)f2bf(v1.y);
        t[6] = (short)f2bf(v1.z); t[7] = (short)f2bf(v1.w);
        a[kk] = t;
    }
#pragma unroll
    for (int jt = 0; jt < 8; jt++) {
        int jb = jt * 16;
        float bias = sb1[jb + lm];
        floatx4 acc = {bias, bias, bias, bias};
#pragma unroll
        for (int kk = 0; kk < 2; kk++) {
            const short8* bp = reinterpret_cast<const short8*>(
                &wB[jb + lm][kk * 32 + quad * 8]);
            acc = __builtin_amdgcn_mfma_f32_16x16x32_bf16(a[kk], *bp, acc, 0, 0, 0);
        }
#pragma unroll
        for (int r = 0; r < 4; r++) {
            int orow = n0 + quad * 4 + r;
            hid[(size_t)orow * HD2 + jb + lm] = f2bf(fmaxf(acc[r], 0.f));
        }
    }
}

// ---- MLP stage 2 (MFMA): h'[n][c] = relu(hid[n][:]@W2[:,c]+b2[c]), K=128,J=64.
// A direct from bf16 hid; W2 transposed to LDS [c][k+8pad].
// Emits fp32 h and bf16 mirror hb.
__global__ void __launch_bounds__(256) k_mlp2(
        const u16* __restrict__ hid,
        const float* __restrict__ W2, const float* __restrict__ b2,
        float* __restrict__ hout, u16* __restrict__ hbout) {
    __shared__ u16 wB[HD][HD2 + 8];   // [c][k], 64*136*2 = 17.4 KB
    __shared__ float sb2[HD];
    int tid = threadIdx.x;
    for (int i = tid; i < HD2 * HD; i += 256) {
        int j = i >> 6, c = i & 63;
        wB[c][j] = f2bf(W2[i]);
    }
    if (tid < HD) sb2[tid] = b2[tid];
    __syncthreads();
    int wid = tid >> 6, lane = tid & 63;
    int quad = lane >> 4, lm = lane & 15;
    int n0 = blockIdx.x * 64 + wid * 16;
    if (n0 >= N_NODES) return;
    int node = n0 + lm;
    short8 a[4];
    const u16* ar = hid + (size_t)node * HD2;
#pragma unroll
    for (int kk = 0; kk < 4; kk++)
        a[kk] = *reinterpret_cast<const short8*>(ar + kk * 32 + quad * 8);
#pragma unroll
    for (int ct = 0; ct < 4; ct++) {
        int cb = ct * 16;
        float bias = sb2[cb + lm];
        floatx4 acc = {bias, bias, bias, bias};
#pragma unroll
        for (int kk = 0; kk < 4; kk++) {
            const short8* bp = reinterpret_cast<const short8*>(
                &wB[cb + lm][kk * 32 + quad * 8]);
            acc = __builtin_amdgcn_mfma_f32_16x16x32_bf16(a[kk], *bp, acc, 0, 0, 0);
        }
#pragma unroll
        for (int r = 0; r < 4; r++) {
            int orow = n0 + quad * 4 + r;
            float o = fmaxf(acc[r], 0.f);
            hout[(size_t)orow * HD + cb + lm] = o;
            hbout[(size_t)orow * HD + cb + lm] = f2bf(o);
        }
    }
}

// One wave per graph; range via inline binary search on sorted batch.
__global__ void __launch_bounds__(256) k_pool(
        const float* __restrict__ h, const int* __restrict__ batch,
        float* __restrict__ pooled) {
    int g = blockIdx.x * 4 + (threadIdx.x >> 6);
    if (g >= N_GRAPHS) return;
    int f = threadIdx.x & 63;
    int lo = 0, hi = N_NODES;
    while (lo < hi) {
        int mid = (lo + hi) >> 1;
        if (batch[mid] < g) lo = mid + 1; else hi = mid;
    }
    int b = lo;
    int lo2 = b, hi2 = N_NODES;
    while (lo2 < hi2) {
        int mid = (lo2 + hi2) >> 1;
        if (batch[mid] < g + 1) lo2 = mid + 1; else hi2 = mid;
    }
    int e = lo2;
    float s = 0.f;
    for (int n = b; n < e; n++) s += h[(size_t)n * HD + f];
    float cnt = fmaxf((float)(e - b), 1.f);
    pooled[(size_t)g * HD + f] = s / cnt;
}

__global__ void __launch_bounds__(64) k_head(
        const float* __restrict__ pooled, const float* __restrict__ gattr,
        const float* __restrict__ d1W, const float* __restrict__ d1b,
        const float* __restrict__ d2W, const float* __restrict__ d2b,
        const float* __restrict__ oW, const float* __restrict__ ob,
        float* __restrict__ out) {
    int g = blockIdx.x;
    __shared__ float si[HD + F_GRAPH];
    __shared__ float s1[32], s2[32];
    int t = threadIdx.x;
    if (t < HD) si[t] = pooled[(size_t)g * HD + t];
    if (t < F_GRAPH) si[HD + t] = gattr[(size_t)g * F_GRAPH + t];
    __syncthreads();
    if (t < 32) {
        float acc = d1b[t];
        for (int i = 0; i < HD + F_GRAPH; i++) acc += si[i] * d1W[i * 32 + t];
        s1[t] = fmaxf(acc, 0.f);
    }
    __syncthreads();
    if (t < 32) {
        float acc = d2b[t];
        for (int i = 0; i < 32; i++) acc += s1[i] * d2W[i * 32 + t];
        s2[t] = fmaxf(acc, 0.f);
    }
    __syncthreads();
    if (t == 0) {
        float acc = ob[0];
        for (int i = 0; i < 32; i++) acc += s2[i] * oW[i];
        out[g] = 1.f / (1.f + __expf(-acc));
    }
}

extern "C" void kernel_launch(void* const* d_in, const int* in_sizes, int n_in,
                              void* d_out, int out_size, void* d_ws, size_t ws_size,
                              hipStream_t stream) {
    const float* x     = (const float*)d_in[0];
    const float* eattr = (const float*)d_in[1];
    const float* gattr = (const float*)d_in[2];
    const int*   eidx  = (const int*)d_in[3];
    const int*   batch = (const int*)d_in[4];
    const float* nodeW = (const float*)d_in[5];
    const float* nodeb = (const float*)d_in[6];
    const float* edgeW = (const float*)d_in[7];
    const float* edgeb = (const float*)d_in[8];
    const float* cW1[3] = {(const float*)d_in[9],  (const float*)d_in[13], (const float*)d_in[17]};
    const float* cb1[3] = {(const float*)d_in[10], (const float*)d_in[14], (const float*)d_in[18]};
    const float* cW2[3] = {(const float*)d_in[11], (const float*)d_in[15], (const float*)d_in[19]};
    const float* cb2[3] = {(const float*)d_in[12], (const float*)d_in[16], (const float*)d_in[20]};
    const float* d1W = (const float*)d_in[21];
    const float* d1b = (const float*)d_in[22];
    const float* d2W = (const float*)d_in[23];
    const float* d2b = (const float*)d_in[24];
    const float* oW  = (const float*)d_in[25];
    const float* ob  = (const float*)d_in[26];

    const int* src = eidx;
    const int* dst = eidx + N_EDGES;

    // workspace layout
    char* p = (char*)d_ws;
    float* h      = (float*)p; p += (size_t)N_NODES * HD * 4;       // 25.6 MB
    float* outb   = (float*)p; p += (size_t)N_NODES * HD * 4;       // 25.6 MB
    u16*   hid    = (u16*)p;   p += (size_t)N_NODES * HD2 * 2;      // 25.6 MB
    unsigned int* rec = (unsigned int*)p; p += (size_t)N_EDGES * F_EDGE * 4; // 51.2 MB
    u16*   hb     = (u16*)p;   p += (size_t)N_NODES * HD * 2;       // 12.8 MB
    float* pooled = (float*)p; p += (size_t)N_GRAPHS * HD * 4;
    int*   off    = (int*)p;   p += (size_t)(N_NODES + 1) * 4;
    int*   deg    = (int*)p;   p += (size_t)N_NODES * 4;
    int*   rank   = (int*)p;   p += (size_t)N_EDGES * 4;            // 6.4 MB
    int*   bsum   = (int*)p;   p += (size_t)(SCAN_NBLK + 1) * 4;
    int*   bpre   = (int*)p;   p += (size_t)(SCAN_NBLK + 1) * 4;

    const int EB = (N_EDGES + 255) / 256;
    const int NBM = (N_NODES + 63) / 64;   // 1563 MFMA blocks (64 nodes each)

    k_node_embed<<<(N_NODES * HD + 255) / 256, 256, 0, stream>>>(x, nodeW, nodeb, h, hb);

    // CSR build (atomic-free scatter via hist-captured ranks)
    hipMemsetAsync(deg, 0, (size_t)N_NODES * 4, stream);
    k_hist<<<EB, 256, 0, stream>>>(dst, deg, rank);
    k_scan1<<<SCAN_NBLK, 256, 0, stream>>>(deg, bsum);
    k_scan2<<<1, 512, 0, stream>>>(bsum, bpre);
    k_scan3<<<SCAN_NBLK, 256, 0, stream>>>(deg, bpre, off);
    k_scatter<<<EB, 256, 0, stream>>>(src, dst, rank, off, eattr, rec);

    for (int l = 0; l < 3; l++) {
        k_gen_agg<<<(N_NODES + 3) / 4, 256, 0, stream>>>(
            h, hb, off, rec, edgeW, edgeb, outb);
        k_mlp1<<<NBM, 256, 0, stream>>>(outb, cW1[l], cb1[l], hid);
        k_mlp2<<<NBM, 256, 0, stream>>>(hid, cW2[l], cb2[l], h, hb);
    }

    k_pool<<<(N_GRAPHS + 3) / 4, 256, 0, stream>>>(h, batch, pooled);
    k_head<<<N_GRAPHS, 64, 0, stream>>>(pooled, gattr,
                                        d1W, d1b, d2W, d2b, oW, ob,
                                        (float*)d_out);
}